// Round 10
// baseline (501.236 us; speedup 1.0000x reference)
//
#include <hip/hip_runtime.h>

// ChildSumTreeLSTMCell — round 10: barrier-free chunk loop + deep prefetch.
// 32 nodes/block, 512 threads, 2 blocks/CU. LDS 54272 B (Axh + wfs; IUOp
// overlays wfs). uh A-fragments are loaded DIRECTLY from h_msgs (contiguous
// 32B/lane, line-coalesced) and packed to bf16 with v_perm_b32 — no Hm, no
// per-chunk barriers. All GEMMs use pairwise (depth-2) B prefetch. iou pass p
// covers contiguous cols p*128..+127 -> fully coalesced final h,c writes.
// Block barriers: 5 total (was 14).

typedef __attribute__((ext_vector_type(8))) short short8;
typedef __attribute__((ext_vector_type(4))) float f32x4;
typedef __attribute__((ext_vector_type(4))) unsigned short us4;
typedef __attribute__((ext_vector_type(4))) unsigned int u32x4;

#define NN 65536

__device__ __forceinline__ unsigned short f2bf(float f) {
  unsigned int u = __float_as_uint(f);
  u += 0x7FFFu + ((u >> 16) & 1u);   // RNE
  return (unsigned short)(u >> 16);
}
__device__ __forceinline__ float bf2f(unsigned short s) {
  return __uint_as_float(((unsigned int)s) << 16);
}
// pack 2 f32 -> (bf16(lo) | bf16(hi)<<16), round-to-nearest-up via +0x8000
__device__ __forceinline__ unsigned int pkbf(float lo, float hi) {
  unsigned int a = __float_as_uint(lo) + 0x8000u;
  unsigned int b = __float_as_uint(hi) + 0x8000u;
  return __builtin_amdgcn_perm(b, a, 0x07060302u);
}
__device__ __forceinline__ f32x4 mfma16(short8 a, short8 b, f32x4 c) {
  return __builtin_amdgcn_mfma_f32_16x16x32_bf16(a, b, c, 0, 0, 0);
}
__device__ __forceinline__ float sigmoidf_(float v) { return 1.0f / (1.0f + __expf(-v)); }
__device__ __forceinline__ float ftanh(float v) { return 1.0f - 2.0f / (__expf(2.0f * v) + 1.0f); }

// ---------------- weight prep ----------------
// frag layout: [kt][ct][lane][8]; lane holds B[k=kt*32+8*(lane>>4)+j][col=ct*16+(lane&15)]
__global__ void prep_all(const float* __restrict__ Wf, const float* __restrict__ Uf,
                         const float* __restrict__ Wiou, const float* __restrict__ Uiou,
                         unsigned short* __restrict__ ws) {
  int idx = blockIdx.x * 256 + threadIdx.x;          // 589824 total
  if (idx < 81920) {                                  // Bwf [10][16][64][8]
    int j = idx & 7, lane = (idx >> 3) & 63, ct = (idx >> 9) & 15, kt = idx >> 13;
    int k = kt*32 + ((lane >> 4) << 3) + j, col = ct*16 + (lane & 15);
    ws[idx] = f2bf(k < 300 ? Wf[col*300 + k] : 0.0f);
  } else if (idx < 147456) {                          // Buf [8][16][64][8]
    int i = idx - 81920;
    int j = i & 7, lane = (i >> 3) & 63, ct = (i >> 9) & 15, kt = i >> 13;
    int k = kt*32 + ((lane >> 4) << 3) + j, col = ct*16 + (lane & 15);
    ws[idx] = f2bf(Uf[col*256 + k]);
  } else {                                            // Biou [18][48][64][8]; ct = cb*3+gate
    int i = idx - 147456;
    int j = i & 7, lane = (i >> 3) & 63;
    int rest = i >> 9, ct = rest % 48, kt = rest / 48;
    int k = kt*32 + ((lane >> 4) << 3) + j;
    int g = (ct % 3)*256 + (ct/3)*16 + (lane & 15);
    float v = (k < 320) ? (k < 300 ? Wiou[g*300 + k] : 0.0f) : Uiou[g*256 + (k - 320)];
    ws[idx] = f2bf(v);
  }
}

// ---------------- fused cell ----------------
__global__ __launch_bounds__(512, 4) void fused_cell(
    const float* __restrict__ x, const float* __restrict__ h_msgs,
    const float* __restrict__ c_msgs,
    const float* __restrict__ b_iou, const float* __restrict__ b_Uiou,
    const float* __restrict__ bWf, const float* __restrict__ bUf,
    const unsigned short* __restrict__ Bwf, const unsigned short* __restrict__ Buf,
    const unsigned short* __restrict__ Biou,
    float* __restrict__ out_h, float* __restrict__ out_c) {
  __shared__ alignas(16) char smem[54272];
  unsigned short* Axh = (unsigned short*)smem;            // [32][584] x | h_tild, 37376 B
  unsigned short* wfs = (unsigned short*)(smem + 37376);  // [32][264] wf+bias,   16896 B
  unsigned int*   IUOp = (unsigned int*)(smem + 37376);   // [32][132] overlay of wfs

  const int tid = threadIdx.x;
  const int n0 = blockIdx.x * 32;
  const int wave = tid >> 6, lane = tid & 63;
  const int lrow = lane & 15, lgrp = lane >> 4;
  const int nl = wave;
  const f32x4 fz = {0.0f, 0.0f, 0.0f, 0.0f};

  // direct-global uh A-frag: 8 contiguous f32 -> bf16 short8
  auto ldA = [&](const float* base, int ks) -> short8 {
    f32x4 v0 = *(const f32x4*)(base + ks*32);
    f32x4 v1 = *(const f32x4*)(base + ks*32 + 4);
    u32x4 u = { pkbf(v0[0], v0[1]), pkbf(v0[2], v0[3]),
                pkbf(v1[0], v1[1]), pkbf(v1[2], v1[3]) };
    return __builtin_bit_cast(short8, u);
  };

  // ---- stage x -> Axh cols 0..319 (zero-pad 300..319)
  for (int i = tid; i < 32*80; i += 512) {
    int r = i / 80, c4 = i - r*80;
    f32x4 v = fz;
    if (c4 < 75) v = *(const f32x4*)&x[(size_t)(n0 + r)*300 + c4*4];
    us4 o;
#pragma unroll
    for (int e = 0; e < 4; ++e) o[e] = f2bf(v[e]);
    *(us4*)&Axh[r*584 + c4*4] = o;
  }
  __syncthreads();                     // B1: Axh-x ready

  // ---- wf GEMM: [32x320]x[320x256] -> wfs (bf16,+bias); pairwise prefetch
  {
    const unsigned short* bw = Bwf + (wave*2*64 + lane)*8;
    short8 c0 = *(const short8*)bw,            c1 = *(const short8*)(bw + 512);
    short8 d0 = *(const short8*)(bw + 8192),   d1 = *(const short8*)(bw + 8704);
    f32x4 w00 = fz, w01 = fz, w10 = fz, w11 = fz;
#pragma unroll
    for (int kk = 0; kk < 5; ++kk) {
      short8 nc0 = c0, nc1 = c1, nd0 = d0, nd1 = d1;
      if (kk < 4) {
        const unsigned short* np = bw + (size_t)(kk*2 + 2)*8192;
        nc0 = *(const short8*)np;          nc1 = *(const short8*)(np + 512);
        nd0 = *(const short8*)(np + 8192); nd1 = *(const short8*)(np + 8704);
      }
      int ks = kk*2;
      short8 a0 = *(const short8*)&Axh[lrow*584 + ks*32 + lgrp*8];
      short8 a1 = *(const short8*)&Axh[(16 + lrow)*584 + ks*32 + lgrp*8];
      w00 = mfma16(a0, c0, w00); w10 = mfma16(a1, c0, w10);
      w01 = mfma16(a0, c1, w01); w11 = mfma16(a1, c1, w11);
      short8 b0 = *(const short8*)&Axh[lrow*584 + (ks+1)*32 + lgrp*8];
      short8 b1 = *(const short8*)&Axh[(16 + lrow)*584 + (ks+1)*32 + lgrp*8];
      w00 = mfma16(b0, d0, w00); w10 = mfma16(b1, d0, w10);
      w01 = mfma16(b0, d1, w01); w11 = mfma16(b1, d1, w11);
      c0 = nc0; c1 = nc1; d0 = nd0; d1 = nd1;
    }
    float bias0 = bWf[wave*32 + lrow];
    float bias1 = bWf[wave*32 + 16 + lrow];
#pragma unroll
    for (int r = 0; r < 4; ++r) {
      wfs[(lgrp*4 + r)*264 + wave*32 + lrow]           = f2bf(w00[r] + bias0);
      wfs[(lgrp*4 + r)*264 + wave*32 + 16 + lrow]      = f2bf(w01[r] + bias1);
      wfs[(16 + lgrp*4 + r)*264 + wave*32 + lrow]      = f2bf(w10[r] + bias0);
      wfs[(16 + lgrp*4 + r)*264 + wave*32 + 16 + lrow] = f2bf(w11[r] + bias1);
    }
  }
  // no barrier: fgates reads only this wave's wfs columns

  const float bu0 = bUf[wave*32 + lrow];
  const float bu1 = bUf[wave*32 + 16 + lrow];

  // ---- 4 chunks, NO barriers: uh GEMM (direct-global A) + in-reg gates
#pragma unroll 1
  for (int chunk = 0; chunk < 4; ++chunk) {
    // h_tild loads (wave's node), consumed after uh
    const float* hp = h_msgs + (size_t)(n0 + chunk*8 + nl)*1024 + lane*4;
    f32x4 t0 = *(const f32x4*)hp;
    f32x4 t1 = *(const f32x4*)(hp + 256);
    f32x4 t2 = *(const f32x4*)(hp + 512);
    f32x4 t3 = *(const f32x4*)(hp + 768);
    // c_msgs scalars (consumed in ct epilogue)
    float cm[2][2][4];
#pragma unroll
    for (int rt = 0; rt < 2; ++rt) {
      const float* cp = c_msgs + (size_t)(n0 + chunk*8 + rt*4 + lgrp)*1024 + wave*32 + lrow;
#pragma unroll
      for (int ct2 = 0; ct2 < 2; ++ct2)
#pragma unroll
        for (int r = 0; r < 4; ++r) cm[rt][ct2][r] = cp[r*256 + ct2*16];
    }

    // uh GEMM, A direct from global, pairwise B prefetch
    const float* hA0 = h_msgs + ((size_t)(n0 + chunk*8 + (lrow >> 2))*4 + (lrow & 3))*256 + lgrp*8;
    const float* hA1 = h_msgs + ((size_t)(n0 + chunk*8 + 4 + (lrow >> 2))*4 + (lrow & 3))*256 + lgrp*8;
    f32x4 a00 = fz, a01 = fz, a10 = fz, a11 = fz;
    const unsigned short* bB = Buf + (wave*2*64 + lane)*8;
    short8 c0 = *(const short8*)bB,          c1 = *(const short8*)(bB + 512);
    short8 d0 = *(const short8*)(bB + 8192), d1 = *(const short8*)(bB + 8704);
#pragma unroll
    for (int kk = 0; kk < 4; ++kk) {
      short8 nc0 = c0, nc1 = c1, nd0 = d0, nd1 = d1;
      if (kk < 3) {
        const unsigned short* np = bB + (size_t)(kk*2 + 2)*8192;
        nc0 = *(const short8*)np;          nc1 = *(const short8*)(np + 512);
        nd0 = *(const short8*)(np + 8192); nd1 = *(const short8*)(np + 8704);
      }
      int ks = kk*2;
      short8 A0 = ldA(hA0, ks),   A1 = ldA(hA1, ks);
      a00 = mfma16(A0, c0, a00);  a01 = mfma16(A0, c1, a01);
      a10 = mfma16(A1, c0, a10);  a11 = mfma16(A1, c1, a11);
      short8 B0 = ldA(hA0, ks+1), B1 = ldA(hA1, ks+1);
      a00 = mfma16(B0, d0, a00);  a01 = mfma16(B0, d1, a01);
      a10 = mfma16(B1, d0, a10);  a11 = mfma16(B1, d1, a11);
      c0 = nc0; c1 = nc1; d0 = nd0; d1 = nd1;
    }

    // h_tild -> Axh (wave-private row)
    {
      us4 ht;
#pragma unroll
      for (int e = 0; e < 4; ++e) ht[e] = f2bf(t0[e] + t1[e] + t2[e] + t3[e]);
      *(us4*)&Axh[(chunk*8 + nl)*584 + 320 + lane*4] = ht;
    }

    // f-gates + c_tild fully in-register; c_tild -> global c-slot
#pragma unroll
    for (int rt = 0; rt < 2; ++rt) {
      int node = chunk*8 + rt*4 + lgrp;
      const f32x4 u0 = rt ? a10 : a00;
      const f32x4 u1 = rt ? a11 : a01;
#pragma unroll
      for (int ct2 = 0; ct2 < 2; ++ct2) {
        const f32x4 uv = ct2 ? u1 : u0;
        int col = wave*32 + ct2*16 + lrow;
        float wfv = bf2f(wfs[node*264 + col]);
        float bus = ct2 ? bu1 : bu0;
        float s = 0.0f;
#pragma unroll
        for (int r = 0; r < 4; ++r)
          s += sigmoidf_(uv[r] + wfv + bus) * cm[rt][ct2][r];
        out_c[(size_t)(n0 + node)*256 + col] = s;
      }
    }
  }
  __syncthreads();                     // B2: h_tild visible; wfs dead -> IUOp ok

  // ---- iou GEMM: [32x576]x[576x768]; pass p covers cols p*128..+127
#pragma unroll 1
  for (int p = 0; p < 2; ++p) {
    int cb = p*8 + wave;               // col-block in [0,16)
    int col = cb*16 + lrow;
    const unsigned short* bi = Biou + ((size_t)(cb*3)*64 + lane)*8;
    short8 g0 = *(const short8*)bi;
    short8 g1 = *(const short8*)(bi + 512);
    short8 g2 = *(const short8*)(bi + 1024);
    short8 k0 = *(const short8*)(bi + 24576);
    short8 k1 = *(const short8*)(bi + 25088);
    short8 k2 = *(const short8*)(bi + 25600);
    f32x4 aI0 = fz, aO0 = fz, aU0 = fz, aI1 = fz, aO1 = fz, aU1 = fz;
#pragma unroll
    for (int kk = 0; kk < 9; ++kk) {
      short8 n0b = g0, n1b = g1, n2b = g2, m0b = k0, m1b = k1, m2b = k2;
      if (kk < 8) {
        const unsigned short* np = bi + (size_t)(kk*2 + 2)*24576;
        n0b = *(const short8*)np;           n1b = *(const short8*)(np + 512);
        n2b = *(const short8*)(np + 1024);  m0b = *(const short8*)(np + 24576);
        m1b = *(const short8*)(np + 25088); m2b = *(const short8*)(np + 25600);
      }
      int ks = kk*2;
      short8 A0 = *(const short8*)&Axh[lrow*584 + ks*32 + lgrp*8];
      short8 A1 = *(const short8*)&Axh[(16 + lrow)*584 + ks*32 + lgrp*8];
      aI0 = mfma16(A0, g0, aI0); aI1 = mfma16(A1, g0, aI1);
      aO0 = mfma16(A0, g1, aO0); aO1 = mfma16(A1, g1, aO1);
      aU0 = mfma16(A0, g2, aU0); aU1 = mfma16(A1, g2, aU1);
      short8 B0 = *(const short8*)&Axh[lrow*584 + (ks+1)*32 + lgrp*8];
      short8 B1 = *(const short8*)&Axh[(16 + lrow)*584 + (ks+1)*32 + lgrp*8];
      aI0 = mfma16(B0, k0, aI0); aI1 = mfma16(B1, k0, aI1);
      aO0 = mfma16(B0, k1, aO0); aO1 = mfma16(B1, k1, aO1);
      aU0 = mfma16(B0, k2, aU0); aU1 = mfma16(B1, k2, aU1);
      g0 = n0b; g1 = n1b; g2 = n2b; k0 = m0b; k1 = m1b; k2 = m2b;
    }
    float bI = b_iou[col]       + b_Uiou[col];
    float bO = b_iou[256 + col] + b_Uiou[256 + col];
    float bU = b_iou[512 + col] + b_Uiou[512 + col];
    // output row rt*16+lgrp*4+r; slot = wave*16+lrow == (col - p*128)
#pragma unroll
    for (int rt = 0; rt < 2; ++rt) {
      f32x4 ai = rt ? aI1 : aI0, ao = rt ? aO1 : aO0, au = rt ? aU1 : aU0;
#pragma unroll
      for (int r = 0; r < 4; ++r) {
        float iv = sigmoidf_(ai[r] + bI);
        float ov = sigmoidf_(ao[r] + bO);
        float uv = ftanh(au[r] + bU);
        IUOp[(rt*16 + lgrp*4 + r)*132 + wave*16 + lrow] =
            (unsigned int)f2bf(iv * uv) | ((unsigned int)f2bf(ov) << 16);
      }
    }
    __syncthreads();                   // B3: IUOp(pass p) visible

    // epilogue: contiguous cols p*128 + slot; fully coalesced
#pragma unroll
    for (int chunkE = 0; chunkE < 4; ++chunkE) {
      int nb = chunkE*8 + nl;
#pragma unroll
      for (int half = 0; half < 2; ++half) {
        int slot = half*64 + lane;
        unsigned int pk = IUOp[nb*132 + slot];
        size_t base = (size_t)(n0 + nb)*256 + p*128 + slot;
        float iu = bf2f((unsigned short)(pk & 0xFFFFu));
        float ov = bf2f((unsigned short)(pk >> 16));
        float c  = iu + out_c[base];
        out_c[base] = c;
        out_h[base] = ov * ftanh(c);
      }
    }
    if (p == 0) __syncthreads();       // B4: IUOp reads done before pass-1 writes
  }
}

extern "C" void kernel_launch(void* const* d_in, const int* in_sizes, int n_in,
                              void* d_out, int out_size, void* d_ws, size_t ws_size,
                              hipStream_t stream) {
  const float* x      = (const float*)d_in[0];
  const float* h_msgs = (const float*)d_in[1];
  const float* c_msgs = (const float*)d_in[2];
  const float* W_iou  = (const float*)d_in[3];
  const float* b_iou  = (const float*)d_in[4];
  const float* U_iou  = (const float*)d_in[5];
  const float* b_Uiou = (const float*)d_in[6];
  const float* W_f    = (const float*)d_in[7];
  const float* b_Wf   = (const float*)d_in[8];
  const float* U_f    = (const float*)d_in[9];
  const float* b_Uf   = (const float*)d_in[10];

  unsigned short* ws   = (unsigned short*)d_ws;
  unsigned short* Bwf  = ws;                    // [10][16][64][8]
  unsigned short* Buf  = ws + 81920;            // [8][16][64][8]
  unsigned short* Biou = ws + 147456;           // [18][48][64][8]

  float* h_slot = (float*)d_out;
  float* c_slot = h_slot + (size_t)NN*256;

  prep_all<<<2304, 256, 0, stream>>>(W_f, U_f, W_iou, U_iou, ws);
  fused_cell<<<NN/32, 512, 0, stream>>>(x, h_msgs, c_msgs, b_iou, b_Uiou,
                                        b_Wf, b_Uf, Bwf, Buf, Biou, h_slot, c_slot);
}

// Round 11
// 391.510 us; speedup vs baseline: 1.2803x; 1.2803x over previous
//
#include <hip/hip_runtime.h>

// ChildSumTreeLSTMCell — round 11: 4-wave blocks, 4 barrier domains/CU.
// 16 nodes/block, 256 threads. LDS 35.6KB = Axh[16][584] (row-permuted by the
// involution p(n)=(n&3)*4+(n>>2)) + Hm[2][16][264] ping-pong (1 barrier/chunk).
// wf result lives in 8 packed bf16 regs (permutation aligns wf-GEMM output
// lanes with the fgates consumer lanes). f-gates + c_tild fully in-register,
// c_tild straight to global c-slot (R8 mechanism). iou: 2 passes x 2 col-blocks,
// per-pass IUOp[16][132] overlays Hm, contiguous coalesced h,c epilogue.

typedef __attribute__((ext_vector_type(8))) short short8;
typedef __attribute__((ext_vector_type(4))) float f32x4;
typedef __attribute__((ext_vector_type(4))) unsigned short us4;

#define NN 65536

__device__ __forceinline__ unsigned short f2bf(float f) {
  unsigned int u = __float_as_uint(f);
  u += 0x7FFFu + ((u >> 16) & 1u);   // RNE
  return (unsigned short)(u >> 16);
}
__device__ __forceinline__ float bf2f(unsigned short s) {
  return __uint_as_float(((unsigned int)s) << 16);
}
__device__ __forceinline__ f32x4 mfma16(short8 a, short8 b, f32x4 c) {
  return __builtin_amdgcn_mfma_f32_16x16x32_bf16(a, b, c, 0, 0, 0);
}
__device__ __forceinline__ float sigmoidf_(float v) { return 1.0f / (1.0f + __expf(-v)); }
__device__ __forceinline__ float ftanh(float v) { return 1.0f - 2.0f / (__expf(2.0f * v) + 1.0f); }

// ---------------- weight prep ----------------
// frag layout: [kt][ct][lane][8]; lane holds B[k=kt*32+8*(lane>>4)+j][col=ct*16+(lane&15)]
__global__ void prep_all(const float* __restrict__ Wf, const float* __restrict__ Uf,
                         const float* __restrict__ Wiou, const float* __restrict__ Uiou,
                         unsigned short* __restrict__ ws) {
  int idx = blockIdx.x * 256 + threadIdx.x;          // 589824 total
  if (idx < 81920) {                                  // Bwf [10][16][64][8]
    int j = idx & 7, lane = (idx >> 3) & 63, ct = (idx >> 9) & 15, kt = idx >> 13;
    int k = kt*32 + ((lane >> 4) << 3) + j, col = ct*16 + (lane & 15);
    ws[idx] = f2bf(k < 300 ? Wf[col*300 + k] : 0.0f);
  } else if (idx < 147456) {                          // Buf [8][16][64][8]
    int i = idx - 81920;
    int j = i & 7, lane = (i >> 3) & 63, ct = (i >> 9) & 15, kt = i >> 13;
    int k = kt*32 + ((lane >> 4) << 3) + j, col = ct*16 + (lane & 15);
    ws[idx] = f2bf(Uf[col*256 + k]);
  } else {                                            // Biou [18][48][64][8]; ct = cb*3+gate
    int i = idx - 147456;
    int j = i & 7, lane = (i >> 3) & 63;
    int rest = i >> 9, ct = rest % 48, kt = rest / 48;
    int k = kt*32 + ((lane >> 4) << 3) + j;
    int g = (ct % 3)*256 + (ct/3)*16 + (lane & 15);
    float v = (k < 320) ? (k < 300 ? Wiou[g*300 + k] : 0.0f) : Uiou[g*256 + (k - 320)];
    ws[idx] = f2bf(v);
  }
}

// ---------------- fused cell ----------------
__global__ __launch_bounds__(256, 4) void fused_cell(
    const float* __restrict__ x, const float* __restrict__ h_msgs,
    const float* __restrict__ c_msgs,
    const float* __restrict__ b_iou, const float* __restrict__ b_Uiou,
    const float* __restrict__ bWf, const float* __restrict__ bUf,
    const unsigned short* __restrict__ Bwf, const unsigned short* __restrict__ Buf,
    const unsigned short* __restrict__ Biou,
    float* __restrict__ out_h, float* __restrict__ out_c) {
  __shared__ alignas(16) unsigned short Axh[16*584];    // permuted rows, 18688 B
  __shared__ alignas(16) unsigned short Hm[2*16*264];   // ping-pong, 16896 B
  unsigned int* IUOp = (unsigned int*)Hm;               // [16][132] u32, 8448 B (= Hm[0])

  const int tid = threadIdx.x;
  const int n0 = blockIdx.x * 16;
  const int wave = tid >> 6, lane = tid & 63;
  const int lrow = lane & 15, lgrp = lane >> 4;
  const int nl = wave;                 // wave owns node nl of each 4-node chunk
  const f32x4 fz = {0.0f, 0.0f, 0.0f, 0.0f};

  f32x4 hvN[4];                        // in-flight h_msgs for the next chunk

  auto issue_h = [&](int chunk) {
    const float* hp = h_msgs + (size_t)(n0 + chunk*4 + nl)*1024 + lane*4;
#pragma unroll
    for (int k = 0; k < 4; ++k) hvN[k] = *(const f32x4*)(hp + k*256);
  };
  auto write_h = [&](int chunk) {      // -> Hm[chunk&1] rows nl*4+k ; h_tild -> Axh row nl*4+chunk
    unsigned short* Hc = Hm + (chunk & 1)*(16*264);
    f32x4 s = fz;
#pragma unroll
    for (int k = 0; k < 4; ++k) {
      us4 o;
#pragma unroll
      for (int e = 0; e < 4; ++e) { s[e] += hvN[k][e]; o[e] = f2bf(hvN[k][e]); }
      *(us4*)&Hc[(nl*4 + k)*264 + lane*4] = o;
    }
    us4 ht;
#pragma unroll
    for (int e = 0; e < 4; ++e) ht[e] = f2bf(s[e]);
    *(us4*)&Axh[(nl*4 + chunk)*584 + 320 + lane*4] = ht;   // p(chunk*4+nl) = nl*4+chunk
  };

  // ---- prologue: issue h0, stage x (permuted rows), write Hm[0], issue h1
  issue_h(0);
  for (int i = tid; i < 16*80; i += 256) {
    int r = i / 80, c4 = i - r*80;
    f32x4 v = fz;
    if (c4 < 75) v = *(const f32x4*)&x[(size_t)(n0 + r)*300 + c4*4];
    us4 o;
#pragma unroll
    for (int e = 0; e < 4; ++e) o[e] = f2bf(v[e]);
    int qr = (r & 3)*4 + (r >> 2);
    *(us4*)&Axh[qr*584 + c4*4] = o;
  }
  write_h(0);
  issue_h(1);
  __syncthreads();                     // B1: Axh-x + Hm[0] ready

  // ---- wf GEMM: [16 x 320] x [320 x 256] -> 8 packed regs (wfpA/wfpB)
  // output row lgrp*4+r (permuted) = true node r*4+lgrp; at chunk, node
  // chunk*4+lgrp needs reg r=chunk -> wfv[ct] = acc[ct][chunk].
  unsigned int wfpA[4], wfpB[4];
  {
    f32x4 a0 = fz, a1 = fz, a2 = fz, a3 = fz;
    const unsigned short* bw = Bwf + ((size_t)(wave*4)*64 + lane)*8;
    short8 b0 = *(const short8*)bw,          b1 = *(const short8*)(bw + 512);
    short8 b2 = *(const short8*)(bw + 1024), b3 = *(const short8*)(bw + 1536);
#pragma unroll
    for (int ks = 0; ks < 10; ++ks) {
      short8 n0b = b0, n1b = b1, n2b = b2, n3b = b3;
      if (ks < 9) {
        const unsigned short* np = Bwf + (((size_t)(ks+1)*16 + wave*4)*64 + lane)*8;
        n0b = *(const short8*)np;          n1b = *(const short8*)(np + 512);
        n2b = *(const short8*)(np + 1024); n3b = *(const short8*)(np + 1536);
      }
      short8 a = *(const short8*)&Axh[lrow*584 + ks*32 + lgrp*8];
      a0 = mfma16(a, b0, a0); a1 = mfma16(a, b1, a1);
      a2 = mfma16(a, b2, a2); a3 = mfma16(a, b3, a3);
      b0 = n0b; b1 = n1b; b2 = n2b; b3 = n3b;
    }
    float bias0 = bWf[wave*64 + lrow],      bias1 = bWf[wave*64 + 16 + lrow];
    float bias2 = bWf[wave*64 + 32 + lrow], bias3 = bWf[wave*64 + 48 + lrow];
#pragma unroll
    for (int r = 0; r < 4; ++r) {
      wfpA[r] = (unsigned int)f2bf(a0[r] + bias0) | ((unsigned int)f2bf(a1[r] + bias1) << 16);
      wfpB[r] = (unsigned int)f2bf(a2[r] + bias2) | ((unsigned int)f2bf(a3[r] + bias3) << 16);
    }
  }

  float bu[4];
#pragma unroll
  for (int ct = 0; ct < 4; ++ct) bu[ct] = bUf[wave*64 + ct*16 + lrow];

  // ---- 4 chunks, 1 barrier each: uh GEMM (Hm ping-pong) + in-reg gates
#pragma unroll
  for (int chunk = 0; chunk < 4; ++chunk) {
    float cm[4][4];                    // [child r][ct]
    {
      const float* cp = c_msgs + (size_t)(n0 + chunk*4 + lgrp)*1024 + wave*64 + lrow;
#pragma unroll
      for (int r = 0; r < 4; ++r)
#pragma unroll
        for (int ct = 0; ct < 4; ++ct) cm[r][ct] = cp[r*256 + ct*16];
    }
    f32x4 acc[4] = {fz, fz, fz, fz};
    {
      const unsigned short* Hc = Hm + (chunk & 1)*(16*264);
      const unsigned short* bB = Buf + ((size_t)(wave*4)*64 + lane)*8;
      short8 b0 = *(const short8*)bB,          b1 = *(const short8*)(bB + 512);
      short8 b2 = *(const short8*)(bB + 1024), b3 = *(const short8*)(bB + 1536);
#pragma unroll
      for (int ks = 0; ks < 8; ++ks) {
        short8 n0b = b0, n1b = b1, n2b = b2, n3b = b3;
        if (ks < 7) {
          const unsigned short* np = Buf + (((size_t)(ks+1)*16 + wave*4)*64 + lane)*8;
          n0b = *(const short8*)np;          n1b = *(const short8*)(np + 512);
          n2b = *(const short8*)(np + 1024); n3b = *(const short8*)(np + 1536);
        }
        short8 a = *(const short8*)&Hc[lrow*264 + ks*32 + lgrp*8];
        acc[0] = mfma16(a, b0, acc[0]); acc[1] = mfma16(a, b1, acc[1]);
        acc[2] = mfma16(a, b2, acc[2]); acc[3] = mfma16(a, b3, acc[3]);
        b0 = n0b; b1 = n1b; b2 = n2b; b3 = n3b;
      }
    }
    // lane holds uh for node chunk*4+lgrp, children r, col wave*64+ct*16+lrow
#pragma unroll
    for (int ct = 0; ct < 4; ++ct) {
      unsigned int wp = (ct < 2) ? wfpA[chunk] : wfpB[chunk];
      float wfv = (ct & 1) ? bf2f((unsigned short)(wp >> 16))
                           : bf2f((unsigned short)(wp & 0xFFFFu));
      float s = 0.0f;
#pragma unroll
      for (int r = 0; r < 4; ++r)
        s += sigmoidf_(acc[ct][r] + wfv + bu[ct]) * cm[r][ct];
      out_c[(size_t)(n0 + chunk*4 + lgrp)*256 + wave*64 + ct*16 + lrow] = s;  // c_tild
    }
    if (chunk < 3) {
      write_h(chunk + 1);              // writes Hm[(chunk+1)&1]: reads of it ended at chunk-1's barrier
      if (chunk < 2) issue_h(chunk + 2);
    }
    __syncthreads();                   // single barrier per chunk
  }
  // last barrier gates: h_tild visible in Axh; Hm dead -> IUOp overlay ok

  // ---- iou GEMM: [16 x 576] x [576 x 768]; pass p covers cols p*128..+127
#pragma unroll 1
  for (int p = 0; p < 2; ++p) {
    int cb0 = p*8 + wave*2;            // two col-blocks cb0, cb0+1
    const unsigned short* bi = Biou + ((size_t)(cb0*3)*64 + lane)*8;
    short8 f0 = *(const short8*)bi,          f1 = *(const short8*)(bi + 512);
    short8 f2 = *(const short8*)(bi + 1024), f3 = *(const short8*)(bi + 1536);
    short8 f4 = *(const short8*)(bi + 2048), f5 = *(const short8*)(bi + 2560);
    f32x4 aI0 = fz, aO0 = fz, aU0 = fz, aI1 = fz, aO1 = fz, aU1 = fz;
#pragma unroll
    for (int ks = 0; ks < 18; ++ks) {
      short8 g0 = f0, g1 = f1, g2 = f2, g3 = f3, g4 = f4, g5 = f5;
      if (ks < 17) {
        const unsigned short* np = Biou + (((size_t)(ks+1)*48 + cb0*3)*64 + lane)*8;
        g0 = *(const short8*)np;          g1 = *(const short8*)(np + 512);
        g2 = *(const short8*)(np + 1024); g3 = *(const short8*)(np + 1536);
        g4 = *(const short8*)(np + 2048); g5 = *(const short8*)(np + 2560);
      }
      short8 a = *(const short8*)&Axh[lrow*584 + ks*32 + lgrp*8];
      aI0 = mfma16(a, f0, aI0); aO0 = mfma16(a, f1, aO0); aU0 = mfma16(a, f2, aU0);
      aI1 = mfma16(a, f3, aI1); aO1 = mfma16(a, f4, aO1); aU1 = mfma16(a, f5, aU1);
      f0 = g0; f1 = g1; f2 = g2; f3 = g3; f4 = g4; f5 = g5;
    }
    // permuted out row lgrp*4+r -> true node r*4+lgrp; slot = col - p*128
#pragma unroll
    for (int j = 0; j < 2; ++j) {
      int col = (cb0 + j)*16 + lrow;
      float bI = b_iou[col]       + b_Uiou[col];
      float bO = b_iou[256 + col] + b_Uiou[256 + col];
      float bU = b_iou[512 + col] + b_Uiou[512 + col];
      f32x4 ai = j ? aI1 : aI0, ao = j ? aO1 : aO0, au = j ? aU1 : aU0;
#pragma unroll
      for (int r = 0; r < 4; ++r) {
        float iv = sigmoidf_(ai[r] + bI);
        float ov = sigmoidf_(ao[r] + bO);
        float uv = ftanh(au[r] + bU);
        IUOp[(r*4 + lgrp)*132 + (wave*2 + j)*16 + lrow] =
            (unsigned int)f2bf(iv * uv) | ((unsigned int)f2bf(ov) << 16);
      }
    }
    __syncthreads();                   // IUOp(pass p) visible

    // epilogue: 16 nodes x 128 contiguous cols, fully coalesced
#pragma unroll
    for (int e = 0; e < 8; ++e) {
      int idx = e*256 + tid;
      int node = idx >> 7, slot = idx & 127;
      unsigned int pk = IUOp[node*132 + slot];
      size_t base = (size_t)(n0 + node)*256 + p*128 + slot;
      float iu = bf2f((unsigned short)(pk & 0xFFFFu));
      float ov = bf2f((unsigned short)(pk >> 16));
      float c  = iu + out_c[base];     // c_tild written earlier this block
      out_c[base] = c;
      out_h[base] = ov * ftanh(c);
    }
    if (p == 0) __syncthreads();       // IUOp reads done before pass-1 writes
  }
}

extern "C" void kernel_launch(void* const* d_in, const int* in_sizes, int n_in,
                              void* d_out, int out_size, void* d_ws, size_t ws_size,
                              hipStream_t stream) {
  const float* x      = (const float*)d_in[0];
  const float* h_msgs = (const float*)d_in[1];
  const float* c_msgs = (const float*)d_in[2];
  const float* W_iou  = (const float*)d_in[3];
  const float* b_iou  = (const float*)d_in[4];
  const float* U_iou  = (const float*)d_in[5];
  const float* b_Uiou = (const float*)d_in[6];
  const float* W_f    = (const float*)d_in[7];
  const float* b_Wf   = (const float*)d_in[8];
  const float* U_f    = (const float*)d_in[9];
  const float* b_Uf   = (const float*)d_in[10];

  unsigned short* ws   = (unsigned short*)d_ws;
  unsigned short* Bwf  = ws;                    // [10][16][64][8]
  unsigned short* Buf  = ws + 81920;            // [8][16][64][8]
  unsigned short* Biou = ws + 147456;           // [18][48][64][8]

  float* h_slot = (float*)d_out;
  float* c_slot = h_slot + (size_t)NN*256;

  prep_all<<<2304, 256, 0, stream>>>(W_f, U_f, W_iou, U_iou, ws);
  fused_cell<<<NN/16, 256, 0, stream>>>(x, h_msgs, c_msgs, b_iou, b_Uiou,
                                        b_Wf, b_Uf, Bwf, Buf, Biou, h_slot, c_slot);
}